// Round 1
// baseline (200.780 us; speedup 1.0000x reference)
//
#include <hip/hip_runtime.h>
#include <math.h>

#define H_IMG 1024
#define W_IMG 1280
#define NPIX (H_IMG * W_IMG)
#define NACC 28            // 21 (JtJ upper tri) + 6 (JtR) + 1 (valid count)
#define NORM_THR 0.93969262f   // float(cos(20 deg))
#define DIST_THR2 0.04f        // 0.2^2, compare squared distance
#define DAMPING 1e-6

// ---------------------------------------------------------------------------
// init: copy pose10 (f32) into workspace pose (f64)
// ---------------------------------------------------------------------------
__global__ __launch_bounds__(64) void icp_init(const float* __restrict__ pose_in,
                                               double* __restrict__ pose_ws) {
    int i = threadIdx.x;
    if (i < 16) pose_ws[i] = (double)pose_in[i];
}

// ---------------------------------------------------------------------------
// reduce: per-pixel residual/Jacobian, accumulate JtJ/JtR/count
// ---------------------------------------------------------------------------
__global__ __launch_bounds__(256) void icp_reduce(
    const float* __restrict__ vert0, const float* __restrict__ vert1,
    const float* __restrict__ norm0, const float* __restrict__ norm1,
    const float* __restrict__ Kmat,
    const double* __restrict__ pose_ws, double* __restrict__ acc)
{
    // uniform pose / intrinsics loads (scalar-cached)
    const float R00 = (float)pose_ws[0],  R01 = (float)pose_ws[1],  R02 = (float)pose_ws[2],  t0 = (float)pose_ws[3];
    const float R10 = (float)pose_ws[4],  R11 = (float)pose_ws[5],  R12 = (float)pose_ws[6],  t1 = (float)pose_ws[7];
    const float R20 = (float)pose_ws[8],  R21 = (float)pose_ws[9],  R22 = (float)pose_ws[10], t2 = (float)pose_ws[11];
    const float fx = Kmat[0], cx = Kmat[2], fy = Kmat[4], cy = Kmat[5];

    float a[NACC];
#pragma unroll
    for (int k = 0; k < NACC; ++k) a[k] = 0.0f;

    const int stride = gridDim.x * blockDim.x;
    for (int idx = blockIdx.x * blockDim.x + threadIdx.x; idx < NPIX; idx += stride) {
        const int base = idx * 3;
        const float v0x = vert0[base], v0y = vert0[base + 1], v0z = vert0[base + 2];
        const float n0x = norm0[base], n0y = norm0[base + 1], n0z = norm0[base + 2];

        // p = R*v0 + t ; n0r = R*n0
        const float px = R00 * v0x + R01 * v0y + R02 * v0z + t0;
        const float py = R10 * v0x + R11 * v0y + R12 * v0z + t1;
        const float pz = R20 * v0x + R21 * v0y + R22 * v0z + t2;
        const float nrx = R00 * n0x + R01 * n0y + R02 * n0z;
        const float nry = R10 * n0x + R11 * n0y + R12 * n0z;
        const float nrz = R20 * n0x + R21 * n0y + R22 * n0z;

        const float u = px / pz * fx + cx;
        const float v = py / pz * fy + cy;
        const bool inview = (u > 0.0f) && (u < (float)(W_IMG - 1)) &&
                            (v > 0.0f) && (v < (float)(H_IMG - 1));

        // round-half-to-even (matches jnp.round), then clip
        const float uf = fminf(fmaxf(rintf(u), 0.0f), (float)(W_IMG - 1));
        const float vf = fminf(fmaxf(rintf(v), 0.0f), (float)(H_IMG - 1));
        const int wbase = ((int)vf * W_IMG + (int)uf) * 3;

        const float r1x = vert1[wbase], r1y = vert1[wbase + 1], r1z = vert1[wbase + 2];
        const float m1x = norm1[wbase], m1y = norm1[wbase + 1], m1z = norm1[wbase + 2];

        const float dx = px - r1x, dy = py - r1y, dz = pz - r1z;

        const bool mask0 = v0z > 0.0f;
        const bool mask1 = r1z > 0.0f;
        const bool normal_ok = (nrx * m1x + nry * m1y + nrz * m1z) > NORM_THR;
        const float d2 = dx * dx + dy * dy + dz * dz;
        const bool occ = (!inview) || (d2 > DIST_THR2);
        const bool valid = (!occ) && mask0 && mask1 && normal_ok;

        if (valid) {
            const float res = m1x * dx + m1y * dy + m1z * dz;
            float J[6];
            J[0] = py * m1z - pz * m1y;   // cross(p, rn1)
            J[1] = pz * m1x - px * m1z;
            J[2] = px * m1y - py * m1x;
            J[3] = m1x; J[4] = m1y; J[5] = m1z;
            int k = 0;
#pragma unroll
            for (int i = 0; i < 6; ++i)
#pragma unroll
                for (int j = i; j < 6; ++j) a[k++] += J[i] * J[j];
#pragma unroll
            for (int i = 0; i < 6; ++i) a[21 + i] += J[i] * res;
            a[27] += 1.0f;
        }
    }

    // wave-64 tree reduction per component
#pragma unroll
    for (int k = 0; k < NACC; ++k) {
        float val = a[k];
        for (int off = 32; off > 0; off >>= 1) val += __shfl_down(val, off, 64);
        a[k] = val;
    }

    __shared__ float sh[4][NACC];
    const int lane = threadIdx.x & 63;
    const int wid  = threadIdx.x >> 6;
    if (lane == 0) {
#pragma unroll
        for (int k = 0; k < NACC; ++k) sh[wid][k] = a[k];
    }
    __syncthreads();
    if (threadIdx.x < NACC) {
        const int k = threadIdx.x;
        double s = (double)sh[0][k] + (double)sh[1][k] + (double)sh[2][k] + (double)sh[3][k];
        atomicAdd(&acc[k], s);
    }
}

// ---------------------------------------------------------------------------
// solve: 6x6 damped solve + exp_se3 + pose update (single thread, f64)
// ---------------------------------------------------------------------------
__global__ __launch_bounds__(64) void icp_solve(const double* __restrict__ acc,
                                                double* __restrict__ pose_ws,
                                                float* __restrict__ out,
                                                int write_out)
{
    if (threadIdx.x != 0) return;

    double JtJ[6][6];
    {
        int k = 0;
        for (int i = 0; i < 6; ++i)
            for (int j = i; j < 6; ++j) { JtJ[i][j] = acc[k]; JtJ[j][i] = acc[k]; ++k; }
    }
    double JtR[6];
    for (int i = 0; i < 6; ++i) JtR[i] = acc[21 + i];

    double tr = 0.0;
    for (int i = 0; i < 6; ++i) tr += JtJ[i][i];

    // augmented system [Hm | -JtR]
    double A[6][7];
    for (int i = 0; i < 6; ++i) {
        for (int j = 0; j < 6; ++j) A[i][j] = JtJ[i][j] + (i == j ? tr * DAMPING : 0.0);
        A[i][6] = -JtR[i];
    }

    // Gaussian elimination with partial pivoting
    for (int c = 0; c < 6; ++c) {
        int piv = c; double mx = fabs(A[c][c]);
        for (int r = c + 1; r < 6; ++r) {
            double ar = fabs(A[r][c]);
            if (ar > mx) { mx = ar; piv = r; }
        }
        if (piv != c) for (int j = 0; j < 7; ++j) { double tmp = A[c][j]; A[c][j] = A[piv][j]; A[piv][j] = tmp; }
        double d = A[c][c];
        if (d == 0.0) d = 1e-30;
        for (int r = c + 1; r < 6; ++r) {
            double f = A[r][c] / d;
            for (int j = c; j < 7; ++j) A[r][j] -= f * A[c][j];
        }
    }
    double xi[6];
    for (int i = 5; i >= 0; --i) {
        double s = A[i][6];
        for (int j = i + 1; j < 6; ++j) s -= A[i][j] * xi[j];
        double d = A[i][i];
        if (d == 0.0) d = 1e-30;
        xi[i] = s / d;
    }

    // exp_se3(xi)
    const double w0 = xi[0], w1 = xi[1], w2 = xi[2];
    const double v0 = xi[3], v1 = xi[4], v2 = xi[5];
    double wh[3][3] = { {0.0, -w2, w1}, {w2, 0.0, -w0}, {-w1, w0, 0.0} };
    double wh2[3][3];
    for (int i = 0; i < 3; ++i)
        for (int j = 0; j < 3; ++j) {
            double s = 0.0;
            for (int k = 0; k < 3; ++k) s += wh[i][k] * wh[k][j];
            wh2[i][j] = s;
        }
    const double theta = sqrt(w0 * w0 + w1 * w1 + w2 * w2);
    const double eps = 1e-8;
    const double ts = (theta > eps) ? theta : eps;
    const double st = sin(ts), ct = cos(ts);
    const double cA = st / ts;
    const double cB = (1.0 - ct) / (ts * ts);
    const double cC = (ts - st) / (ts * ts * ts);
    const bool small = (theta <= eps);

    double ew[3][3], Jm[3][3];
    for (int i = 0; i < 3; ++i)
        for (int j = 0; j < 3; ++j) {
            double eye = (i == j) ? 1.0 : 0.0;
            ew[i][j] = small ? eye : (eye + cA * wh[i][j] + cB * wh2[i][j]);
            Jm[i][j] = small ? eye : (eye + cB * wh[i][j] + cC * wh2[i][j]);
        }
    double Jv[3];
    for (int i = 0; i < 3; ++i) Jv[i] = Jm[i][0] * v0 + Jm[i][1] * v1 + Jm[i][2] * v2;

    double T[16] = { ew[0][0], ew[0][1], ew[0][2], Jv[0],
                     ew[1][0], ew[1][1], ew[1][2], Jv[1],
                     ew[2][0], ew[2][1], ew[2][2], Jv[2],
                     0.0, 0.0, 0.0, 1.0 };

    double P[16];
    for (int i = 0; i < 16; ++i) P[i] = pose_ws[i];
    double NP[16];
    for (int i = 0; i < 4; ++i)
        for (int j = 0; j < 4; ++j) {
            double s = 0.0;
            for (int k = 0; k < 4; ++k) s += T[i * 4 + k] * P[k * 4 + j];
            NP[i * 4 + j] = s;
        }
    for (int i = 0; i < 16; ++i) pose_ws[i] = NP[i];

    if (write_out) {
        for (int i = 0; i < 16; ++i) out[i] = (float)NP[i];
        out[16] = (float)(acc[27] / (double)NPIX);
    }
}

// ---------------------------------------------------------------------------
extern "C" void kernel_launch(void* const* d_in, const int* in_sizes, int n_in,
                              void* d_out, int out_size, void* d_ws, size_t ws_size,
                              hipStream_t stream) {
    const float* pose10 = (const float*)d_in[0];
    const float* vert0  = (const float*)d_in[1];
    const float* vert1  = (const float*)d_in[2];
    const float* norm0  = (const float*)d_in[3];
    const float* norm1  = (const float*)d_in[4];
    const float* Kmat   = (const float*)d_in[5];
    float* out = (float*)d_out;

    double* pose_ws = (double*)d_ws;
    double* acc     = pose_ws + 16;

    icp_init<<<1, 64, 0, stream>>>(pose10, pose_ws);
    for (int it = 0; it < 3; ++it) {
        hipMemsetAsync(acc, 0, NACC * sizeof(double), stream);
        icp_reduce<<<1024, 256, 0, stream>>>(vert0, vert1, norm0, norm1, Kmat, pose_ws, acc);
        icp_solve<<<1, 64, 0, stream>>>(acc, pose_ws, out, it == 2 ? 1 : 0);
    }
}

// Round 2
// 194.529 us; speedup vs baseline: 1.0321x; 1.0321x over previous
//
#include <hip/hip_runtime.h>
#include <math.h>

#define H_IMG 1024
#define W_IMG 1280
#define NPIX (H_IMG * W_IMG)
#define NQUAD (NPIX / 4)          // 327680
#define RBLOCKS 256
#define RTPB 256
#define QPT (NQUAD / (RBLOCKS * RTPB))   // 5 quads (20 px) per thread, exact
#define NACC 28                    // 21 JtJ upper-tri + 6 JtR + 1 count
#define NREP 8                     // atomic replicas (spread same-address chains)
#define NORM_THR 0.93969262f       // float(cos(20 deg))
#define DIST_THR2 0.04f            // 0.2^2
#define DAMPING 1e-6

// ws layout (doubles): [0..15] pose (f64)
//                      [16 .. 16+NREP*NACC*8) acc slots, each padded to 64B line
//                      then one unsigned counter
#define ACC_DOUBLES (NREP * NACC * 8)

// ---------------------------------------------------------------------------
__global__ __launch_bounds__(256) void icp_init(const float* __restrict__ pose_in,
                                                double* __restrict__ ws) {
    const int i = threadIdx.x;
    if (i < 16) ws[i] = (double)pose_in[i];
    for (int k = i; k < ACC_DOUBLES; k += 256) ws[16 + k] = 0.0;
    if (i == 0) *(unsigned*)(ws + 16 + ACC_DOUBLES) = 0u;
}

// ---------------------------------------------------------------------------
// 6x6 damped solve + exp_se3 + pose update, single thread, f64.
// tot[0..20] = JtJ upper tri, tot[21..26] = JtR, tot[27] = valid count.
__device__ void solve_and_update(const double* tot, double* pose_ws,
                                 float* out, int write_out) {
    double JtJ[6][6];
    {
        int k = 0;
        for (int i = 0; i < 6; ++i)
            for (int j = i; j < 6; ++j) { JtJ[i][j] = tot[k]; JtJ[j][i] = tot[k]; ++k; }
    }
    double tr = 0.0;
    for (int i = 0; i < 6; ++i) tr += JtJ[i][i];

    double A[6][7];
    for (int i = 0; i < 6; ++i) {
        for (int j = 0; j < 6; ++j) A[i][j] = JtJ[i][j] + (i == j ? tr * DAMPING : 0.0);
        A[i][6] = -tot[21 + i];
    }
    // Gaussian elimination w/ partial pivoting
    for (int c = 0; c < 6; ++c) {
        int piv = c; double mx = fabs(A[c][c]);
        for (int r = c + 1; r < 6; ++r) {
            double ar = fabs(A[r][c]);
            if (ar > mx) { mx = ar; piv = r; }
        }
        if (piv != c) for (int j = 0; j < 7; ++j) { double tmp = A[c][j]; A[c][j] = A[piv][j]; A[piv][j] = tmp; }
        double d = A[c][c]; if (d == 0.0) d = 1e-30;
        for (int r = c + 1; r < 6; ++r) {
            double f = A[r][c] / d;
            for (int j = c; j < 7; ++j) A[r][j] -= f * A[c][j];
        }
    }
    double xi[6];
    for (int i = 5; i >= 0; --i) {
        double s = A[i][6];
        for (int j = i + 1; j < 6; ++j) s -= A[i][j] * xi[j];
        double d = A[i][i]; if (d == 0.0) d = 1e-30;
        xi[i] = s / d;
    }

    const double w0 = xi[0], w1 = xi[1], w2 = xi[2];
    const double v0 = xi[3], v1 = xi[4], v2 = xi[5];
    double wh[3][3] = { {0.0, -w2, w1}, {w2, 0.0, -w0}, {-w1, w0, 0.0} };
    double wh2[3][3];
    for (int i = 0; i < 3; ++i)
        for (int j = 0; j < 3; ++j) {
            double s = 0.0;
            for (int k = 0; k < 3; ++k) s += wh[i][k] * wh[k][j];
            wh2[i][j] = s;
        }
    const double theta = sqrt(w0 * w0 + w1 * w1 + w2 * w2);
    const double eps = 1e-8;
    const double ts = (theta > eps) ? theta : eps;
    const double st = sin(ts), ct = cos(ts);
    const double cA = st / ts;
    const double cB = (1.0 - ct) / (ts * ts);
    const double cC = (ts - st) / (ts * ts * ts);
    const bool small = (theta <= eps);

    double ew[3][3], Jm[3][3];
    for (int i = 0; i < 3; ++i)
        for (int j = 0; j < 3; ++j) {
            double eye = (i == j) ? 1.0 : 0.0;
            ew[i][j] = small ? eye : (eye + cA * wh[i][j] + cB * wh2[i][j]);
            Jm[i][j] = small ? eye : (eye + cB * wh[i][j] + cC * wh2[i][j]);
        }
    double Jv[3];
    for (int i = 0; i < 3; ++i) Jv[i] = Jm[i][0] * v0 + Jm[i][1] * v1 + Jm[i][2] * v2;

    double T[16] = { ew[0][0], ew[0][1], ew[0][2], Jv[0],
                     ew[1][0], ew[1][1], ew[1][2], Jv[1],
                     ew[2][0], ew[2][1], ew[2][2], Jv[2],
                     0.0, 0.0, 0.0, 1.0 };
    double P[16];
    for (int i = 0; i < 16; ++i) P[i] = pose_ws[i];
    double NP[16];
    for (int i = 0; i < 4; ++i)
        for (int j = 0; j < 4; ++j) {
            double s = 0.0;
            for (int k = 0; k < 4; ++k) s += T[i * 4 + k] * P[k * 4 + j];
            NP[i * 4 + j] = s;
        }
    for (int i = 0; i < 16; ++i) pose_ws[i] = NP[i];

    if (write_out) {
        for (int i = 0; i < 16; ++i) out[i] = (float)NP[i];
        out[16] = (float)(tot[27] / (double)NPIX);
    }
}

// ---------------------------------------------------------------------------
__global__ __launch_bounds__(RTPB) void icp_fused(
    const float* __restrict__ vert0, const float* __restrict__ vert1,
    const float* __restrict__ norm0, const float* __restrict__ norm1,
    const float* __restrict__ Kmat, double* __restrict__ ws,
    float* __restrict__ out, int write_out)
{
    const double* pose = ws;
    double* acc = ws + 16;
    unsigned* counter = (unsigned*)(ws + 16 + ACC_DOUBLES);

    const float R00 = (float)pose[0],  R01 = (float)pose[1],  R02 = (float)pose[2],  t0 = (float)pose[3];
    const float R10 = (float)pose[4],  R11 = (float)pose[5],  R12 = (float)pose[6],  t1 = (float)pose[7];
    const float R20 = (float)pose[8],  R21 = (float)pose[9],  R22 = (float)pose[10], t2 = (float)pose[11];
    const float fx = Kmat[0], cx = Kmat[2], fy = Kmat[4], cy = Kmat[5];

    float a[NACC];
#pragma unroll
    for (int k = 0; k < NACC; ++k) a[k] = 0.0f;

    auto do_pixel = [&](float v0x, float v0y, float v0z,
                        float n0x, float n0y, float n0z) {
        const float px = R00 * v0x + R01 * v0y + R02 * v0z + t0;
        const float py = R10 * v0x + R11 * v0y + R12 * v0z + t1;
        const float pz = R20 * v0x + R21 * v0y + R22 * v0z + t2;
        const float nrx = R00 * n0x + R01 * n0y + R02 * n0z;
        const float nry = R10 * n0x + R11 * n0y + R12 * n0z;
        const float nrz = R20 * n0x + R21 * n0y + R22 * n0z;

        const float u = px / pz * fx + cx;
        const float v = py / pz * fy + cy;
        const bool inview = (u > 0.0f) && (u < (float)(W_IMG - 1)) &&
                            (v > 0.0f) && (v < (float)(H_IMG - 1));

        const float uf = fminf(fmaxf(rintf(u), 0.0f), (float)(W_IMG - 1));
        const float vf = fminf(fmaxf(rintf(v), 0.0f), (float)(H_IMG - 1));
        const int wbase = ((int)vf * W_IMG + (int)uf) * 3;

        const float r1x = vert1[wbase], r1y = vert1[wbase + 1], r1z = vert1[wbase + 2];
        const float m1x = norm1[wbase], m1y = norm1[wbase + 1], m1z = norm1[wbase + 2];

        const float dx = px - r1x, dy = py - r1y, dz = pz - r1z;
        const bool mask0 = v0z > 0.0f;
        const bool mask1 = r1z > 0.0f;
        const bool normal_ok = (nrx * m1x + nry * m1y + nrz * m1z) > NORM_THR;
        const float d2 = dx * dx + dy * dy + dz * dz;
        const bool occ = (!inview) || (d2 > DIST_THR2);
        const bool valid = (!occ) && mask0 && mask1 && normal_ok;

        if (valid) {
            const float res = m1x * dx + m1y * dy + m1z * dz;
            float J[6];
            J[0] = py * m1z - pz * m1y;
            J[1] = pz * m1x - px * m1z;
            J[2] = px * m1y - py * m1x;
            J[3] = m1x; J[4] = m1y; J[5] = m1z;
            int k = 0;
#pragma unroll
            for (int i = 0; i < 6; ++i)
#pragma unroll
                for (int j = i; j < 6; ++j) a[k++] += J[i] * J[j];
#pragma unroll
            for (int i = 0; i < 6; ++i) a[21 + i] += J[i] * res;
            a[27] += 1.0f;
        }
    };

    const int tid0 = blockIdx.x * RTPB + threadIdx.x;
    const float4* v0q = (const float4*)vert0;
    const float4* n0q = (const float4*)norm0;

#pragma unroll
    for (int i = 0; i < QPT; ++i) {
        const int q = tid0 + i * (RBLOCKS * RTPB);
        const float4 A0 = v0q[q * 3 + 0], A1 = v0q[q * 3 + 1], A2 = v0q[q * 3 + 2];
        const float4 B0 = n0q[q * 3 + 0], B1 = n0q[q * 3 + 1], B2 = n0q[q * 3 + 2];
        do_pixel(A0.x, A0.y, A0.z, B0.x, B0.y, B0.z);
        do_pixel(A0.w, A1.x, A1.y, B0.w, B1.x, B1.y);
        do_pixel(A1.z, A1.w, A2.x, B1.z, B1.w, B2.x);
        do_pixel(A2.y, A2.z, A2.w, B2.y, B2.z, B2.w);
    }

    // wave-64 tree reduction per component
#pragma unroll
    for (int k = 0; k < NACC; ++k) {
        float val = a[k];
        for (int off = 32; off > 0; off >>= 1) val += __shfl_down(val, off, 64);
        a[k] = val;
    }

    __shared__ float sh[4][NACC];
    const int lane = threadIdx.x & 63;
    const int wid  = threadIdx.x >> 6;
    if (lane == 0) {
#pragma unroll
        for (int k = 0; k < NACC; ++k) sh[wid][k] = a[k];
    }
    __syncthreads();

    const unsigned tid = threadIdx.x;
    const int rep = blockIdx.x & (NREP - 1);
    if (tid < NACC) {
        double s = (double)sh[0][tid] + (double)sh[1][tid] +
                   (double)sh[2][tid] + (double)sh[3][tid];
        atomicAdd(&acc[(rep * NACC + (int)tid) * 8], s);
        __threadfence();   // this thread's atomic complete before barrier
    }
    __syncthreads();

    __shared__ bool amLast;
    if (tid == 0) {
        unsigned prev = atomicAdd(counter, 1u);
        amLast = (prev == gridDim.x - 1);
    }
    __syncthreads();

    if (amLast) {
        __shared__ double tot[NACC];
        if (tid < NACC) {
            double s = 0.0;
            for (int r = 0; r < NREP; ++r)
                s += atomicAdd(&acc[(r * NACC + (int)tid) * 8], 0.0);  // coherent read
            tot[tid] = s;
            for (int r = 0; r < NREP; ++r)                              // re-zero for next launch
                atomicExch((unsigned long long*)&acc[(r * NACC + (int)tid) * 8], 0ull);
        }
        if (tid == 0) atomicExch(counter, 0u);
        __syncthreads();
        if (tid == 0) solve_and_update(tot, ws, out, write_out);
    }
}

// ---------------------------------------------------------------------------
extern "C" void kernel_launch(void* const* d_in, const int* in_sizes, int n_in,
                              void* d_out, int out_size, void* d_ws, size_t ws_size,
                              hipStream_t stream) {
    const float* pose10 = (const float*)d_in[0];
    const float* vert0  = (const float*)d_in[1];
    const float* vert1  = (const float*)d_in[2];
    const float* norm0  = (const float*)d_in[3];
    const float* norm1  = (const float*)d_in[4];
    const float* Kmat   = (const float*)d_in[5];
    float* out = (float*)d_out;
    double* ws = (double*)d_ws;

    icp_init<<<1, 256, 0, stream>>>(pose10, ws);
    for (int it = 0; it < 3; ++it) {
        icp_fused<<<RBLOCKS, RTPB, 0, stream>>>(vert0, vert1, norm0, norm1,
                                                Kmat, ws, out, it == 2 ? 1 : 0);
    }
}